// Round 2
// baseline (126.028 us; speedup 1.0000x reference)
//
#include <hip/hip_runtime.h>
#include <math.h>

#define CAPV 2560

__device__ __forceinline__ float wave_sum64(float v) {
#pragma unroll
  for (int o = 32; o; o >>= 1) v += __shfl_xor(v, o, 64);
  return v;
}

__device__ __forceinline__ float silu_f(float t) {
  return t / (1.f + __expf(-t));
}

// ---------------- routing: 1 block, 256 threads (one per patch) ----------------
// Also pre-transposes stem/expert weights into ws for ci-contiguous scalar loads.
__global__ __launch_bounds__(256) void routing_kernel(
    const float* __restrict__ gate_w, const float* __restrict__ gate_b,
    const float* __restrict__ stem_w, const float* __restrict__ exp_w,
    int* __restrict__ route_e, float* __restrict__ route_gate,
    int* __restrict__ route_cpre, int* __restrict__ route_Ce,
    float* __restrict__ stemT, float* __restrict__ wT,
    float* __restrict__ d_scalars) {
  const int p = threadIdx.x;            // patch index 0..255
  const int lane = p & 63, wv = p >> 6; // 4 waves
  const int hp = p >> 4, wp = p & 15;

  // weight transposes
  // stemT[ci*72 + co*9 + k] = stem_w[(co*3+ci)*9 + k]
  if (p < 216) {
    int ci = p / 72, r = p % 72;
    int co = r / 9, k = r % 9;
    stemT[p] = stem_w[(co * 3 + ci) * 9 + k];
  }
  // wT[le*576 + ci*72 + co*9 + k] = exp_w[((le*8+co)*8+ci)*9 + k]
  for (int i = p; i < 9216; i += 256) {
    int le = i / 576, r = i % 576;
    int ci = r / 72, r2 = r % 72;
    int co = r2 / 9, k = r2 % 9;
    wT[i] = exp_w[((le * 8 + co) * 8 + ci) * 9 + k];
  }

  // pooled fourier features (mean over 8x8 patch)
  float pool[18];
  {
    float my = 0.f, mx_ = 0.f;
    float msy[4] = {0, 0, 0, 0}, mcy[4] = {0, 0, 0, 0};
    float msx[4] = {0, 0, 0, 0}, mcx[4] = {0, 0, 0, 0};
#pragma unroll
    for (int r = 0; r < 8; ++r) {
      float yv = -1.f + (2.f / 127.f) * (float)(hp * 8 + r);
      float xv = -1.f + (2.f / 127.f) * (float)(wp * 8 + r);
      my += yv; mx_ += xv;
#pragma unroll
      for (int k = 0; k < 4; ++k) {
        float fr = 3.14159265358979323846f * (float)(1 << k);
        msy[k] += sinf(fr * yv); mcy[k] += cosf(fr * yv);
        msx[k] += sinf(fr * xv); mcx[k] += cosf(fr * xv);
      }
    }
    pool[0] = my * 0.125f; pool[1] = mx_ * 0.125f;
#pragma unroll
    for (int k = 0; k < 4; ++k) {
      pool[2 + 4 * k] = msy[k] * 0.125f;
      pool[3 + 4 * k] = mcy[k] * 0.125f;
      pool[4 + 4 * k] = msx[k] * 0.125f;
      pool[5 + 4 * k] = mcx[k] * 0.125f;
    }
  }

  __shared__ float sWP[4][8];   // per-wave prob sums
  __shared__ float sWZ[4];      // per-wave lse^2 sums
  __shared__ int sWCnt[4][8];   // per-wave expert counts
  __shared__ float sMeanP[8], sFrac[8];
  __shared__ float sAcc[2];
  if (p == 0) { sAcc[0] = 0.f; sAcc[1] = 0.f; }

  for (int l = 0; l < 2; ++l) {
    float logit[8];
#pragma unroll
    for (int e = 0; e < 8; ++e) logit[e] = gate_b[l * 8 + e];
#pragma unroll
    for (int c = 0; c < 18; ++c) {
      float pl = pool[c];
#pragma unroll
      for (int e = 0; e < 8; ++e)
        logit[e] = fmaf(pl, gate_w[(l * 18 + c) * 8 + e], logit[e]);
    }
    float mxv = logit[0]; int em = 0;
#pragma unroll
    for (int e = 1; e < 8; ++e)
      if (logit[e] > mxv) { mxv = logit[e]; em = e; }
    float pr[8]; float se = 0.f;
#pragma unroll
    for (int e = 0; e < 8; ++e) { pr[e] = expf(logit[e] - mxv); se += pr[e]; }
    float inv = 1.f / se;
#pragma unroll
    for (int e = 0; e < 8; ++e) pr[e] *= inv;
    float lse = mxv + logf(se);
    float gate_val = inv; // prob at argmax

    unsigned long long meq[8];
#pragma unroll
    for (int e = 0; e < 8; ++e) meq[e] = __ballot(em == e);
    unsigned long long mm = meq[0];
#pragma unroll
    for (int e = 1; e < 8; ++e) mm = (em == e) ? meq[e] : mm;
    unsigned long long below = (2ull << lane) - 1ull; // inclusive
    int cpre_w = (int)__popcll(mm & below);
    if (lane < 8) {
      unsigned long long t = meq[0];
#pragma unroll
      for (int e = 1; e < 8; ++e) t = (lane == e) ? meq[e] : t;
      sWCnt[wv][lane] = (int)__popcll(t);
    }
    float z2 = wave_sum64(lse * lse);
    if (lane == 0) sWZ[wv] = z2;
#pragma unroll
    for (int e = 0; e < 8; ++e) {
      float s = wave_sum64(pr[e]);
      if (lane == 0) sWP[wv][e] = s;
    }
    __syncthreads();

    int cpre = cpre_w;
#pragma unroll
    for (int w2 = 0; w2 < 4; ++w2)
      if (w2 < wv) cpre += sWCnt[w2][em];

    route_e[l * 256 + p] = em;
    route_gate[l * 256 + p] = gate_val;
    route_cpre[l * 256 + p] = cpre;

    if (p < 8) {
      int ce = sWCnt[0][p] + sWCnt[1][p] + sWCnt[2][p] + sWCnt[3][p];
      route_Ce[l * 8 + p] = ce;
      int kept = 0;
      for (int bb = 0; bb < 64; ++bb) {
        int r = CAPV - bb * ce;
        r = r < 0 ? 0 : r;
        kept += (r < ce ? r : ce);
      }
      sFrac[p] = (float)kept * (1.f / 16384.f);
      sMeanP[p] = (sWP[0][p] + sWP[1][p] + sWP[2][p] + sWP[3][p]) * (1.f / 256.f);
    }
    __syncthreads();
    if (p == 0) {
      float s = 0.f;
#pragma unroll
      for (int e = 0; e < 8; ++e) s += sMeanP[e] * sFrac[e];
      sAcc[1] += 8.f * s;
      sAcc[0] += (sWZ[0] + sWZ[1] + sWZ[2] + sWZ[3]) * (1.f / 256.f);
    }
    __syncthreads();
  }
  if (p == 0) { d_scalars[0] = sAcc[0]; d_scalars[1] = sAcc[1]; }
}

// ---------------- token kernel: 4 tokens per 256-thread block ----------------
__global__ __launch_bounds__(256) void token_kernel(
    const float* __restrict__ X,
    const float* __restrict__ stemT, const float* __restrict__ stem_sc,
    const float* __restrict__ stem_bi,
    const float* __restrict__ wT, const float* __restrict__ exp_b,
    const float* __restrict__ gn_s, const float* __restrict__ gn_b,
    const int* __restrict__ route_e, const float* __restrict__ route_gate,
    const int* __restrict__ route_cpre, const int* __restrict__ route_Ce,
    float* __restrict__ blk_sums) {
  const int g = blockIdx.x;
  const int b = g >> 6, r6 = g & 63;
  const int hp = r6 >> 2, wq = r6 & 3;      // 4 horizontally adjacent patches
  const int tid = threadIdx.x;
  const int w = tid >> 6, lane = tid & 63;  // wave == token
  const int y = lane >> 3, x = lane & 7;
  const int p = hp * 16 + wq * 4 + w;

  __shared__ float sX[3][10][36];    // shared halo for the 4 patches (34 used)
  __shared__ float sT[4][8][10][10]; // per-token buffer, zero border
  __shared__ float sRed[4][12];

  // zero own token buffer (only border survives; interior overwritten)
  {
    float4 z4 = {0.f, 0.f, 0.f, 0.f};
    float4* t4 = (float4*)(&sT[w][0][0][0]);
#pragma unroll
    for (int i = lane; i < 200; i += 64) t4[i] = z4;
  }

  // cooperative coalesced halo load: 3 x 10 x 34 region
  const int gy0 = hp * 8 - 1, gx0 = wq * 32 - 1;
#pragma unroll
  for (int k = 0; k < 4; ++k) {
    int i = tid + k * 256;
    if (i < 1020) {
      int ci = i / 340, rem = i - ci * 340;
      int r = rem / 34, c = rem - r * 34;
      int gy = gy0 + r, gx = gx0 + c;
      float v = 0.f;
      if (gy >= 0 && gy < 128 && gx >= 0 && gx < 128)
        v = X[((b * 3 + ci) * 128 + gy) * 128 + gx];
      sX[ci][r][c] = v;
    }
  }
  __syncthreads();

  // stem conv 3->8 + affine + SiLU (ci-contiguous scalar weights)
  const int xb = w * 8 + x;
  {
    float acc[8];
#pragma unroll
    for (int co = 0; co < 8; ++co) acc[co] = 0.f;
#pragma unroll
    for (int ci = 0; ci < 3; ++ci) {
      float v[9];
#pragma unroll
      for (int dy = 0; dy < 3; ++dy)
#pragma unroll
        for (int dx = 0; dx < 3; ++dx)
          v[dy * 3 + dx] = sX[ci][y + dy][xb + dx];
      const float* __restrict__ wr = stemT + ci * 72;
#pragma unroll
      for (int co = 0; co < 8; ++co)
#pragma unroll
        for (int k = 0; k < 9; ++k)
          acc[co] = fmaf(wr[co * 9 + k], v[k], acc[co]);
    }
#pragma unroll
    for (int co = 0; co < 8; ++co) {
      float t = fmaf(acc[co], stem_sc[co], stem_bi[co]);
      sT[w][co][y + 1][x + 1] = silu_f(t);
    }
  }
  // sT[w] is private to this wave; DS ops complete in order within a wave,
  // so no barrier is needed from here on for sT.

  float a[8];
#pragma unroll
  for (int l = 0; l < 2; ++l) {
    int e = route_e[l * 256 + p];
    e = __builtin_amdgcn_readfirstlane(e);  // wave-uniform -> scalar weight loads
    float gp = route_gate[l * 256 + p];
    int cpre = route_cpre[l * 256 + p];
    int Ce = route_Ce[l * 8 + e];
    float gate = (b * Ce + cpre <= CAPV) ? gp : 0.f;
    const float* __restrict__ wbase = wT + (size_t)(l * 8 + e) * 576;
    const float* __restrict__ wb = exp_b + (size_t)(l * 8 + e) * 8;

#pragma unroll
    for (int co = 0; co < 8; ++co) a[co] = wb[co];
#pragma unroll
    for (int ci = 0; ci < 8; ++ci) {
      float v[9];
#pragma unroll
      for (int dy = 0; dy < 3; ++dy)
#pragma unroll
        for (int dx = 0; dx < 3; ++dx)
          v[dy * 3 + dx] = sT[w][ci][y + dy][x + dx];
      const float* __restrict__ wr = wbase + ci * 72;  // 72 contiguous floats
#pragma unroll
      for (int co = 0; co < 8; ++co)
#pragma unroll
        for (int k = 0; k < 9; ++k)
          a[co] = fmaf(wr[co * 9 + k], v[k], a[co]);
    }
#pragma unroll
    for (int co = 0; co < 8; ++co) a[co] = silu_f(a[co]) * gate;

    if (l == 0) {
      // per-token GroupNorm (4 groups of 2 channels x 64 spatial)
      float mu[4], invs[4];
#pragma unroll
      for (int g4 = 0; g4 < 4; ++g4) {
        float s = a[2 * g4] + a[2 * g4 + 1];
        float q = a[2 * g4] * a[2 * g4] + a[2 * g4 + 1] * a[2 * g4 + 1];
        s = wave_sum64(s);
        q = wave_sum64(q);
        float m = s * (1.f / 128.f);
        float var = q * (1.f / 128.f) - m * m;
        mu[g4] = m;
        invs[g4] = rsqrtf(var + 1e-5f);
      }
#pragma unroll
      for (int co = 0; co < 8; ++co) {
        int g2 = co >> 1;
        sT[w][co][y + 1][x + 1] = fmaf((a[co] - mu[g2]) * invs[g2], gn_s[co], gn_b[co]);
      }
    }
  }

  // per-token partial sums: 8 channel sums + 4 group sum-of-squares
  float red[12];
#pragma unroll
  for (int co = 0; co < 8; ++co) red[co] = a[co];
#pragma unroll
  for (int g4 = 0; g4 < 4; ++g4)
    red[8 + g4] = a[2 * g4] * a[2 * g4] + a[2 * g4 + 1] * a[2 * g4 + 1];
#pragma unroll
  for (int j = 0; j < 12; ++j) red[j] = wave_sum64(red[j]);
  if (lane == 0) {
#pragma unroll
    for (int j = 0; j < 12; ++j) sRed[w][j] = red[j];
  }
  __syncthreads();
  if (tid < 12)
    blk_sums[(size_t)g * 12 + tid] =
        sRed[0][tid] + sRed[1][tid] + sRed[2][tid] + sRed[3][tid];
}

// ---------------- finish: per-image GN-folded pooling + MLP head ----------------
__global__ __launch_bounds__(64) void finish_kernel(
    const float* __restrict__ blk_sums,
    const float* __restrict__ gn_s, const float* __restrict__ gn_b,
    const float* __restrict__ w1, const float* __restrict__ b1,
    const float* __restrict__ w2, const float* __restrict__ b2,
    float* __restrict__ out) {
  const int b = blockIdx.x;
  const int lane = threadIdx.x;

  const float4* s4 = (const float4*)(blk_sums + (size_t)(b * 64 + lane) * 12);
  float4 a0 = s4[0], a1 = s4[1], a2 = s4[2];
  float l0[12] = {a0.x, a0.y, a0.z, a0.w, a1.x, a1.y, a1.z, a1.w,
                  a2.x, a2.y, a2.z, a2.w};
#pragma unroll
  for (int j = 0; j < 12; ++j) l0[j] = wave_sum64(l0[j]);

  float pooled[8];
#pragma unroll
  for (int c = 0; c < 8; ++c) {
    int gg = c >> 1;
    float mean_c = l0[c] * (1.f / 16384.f);
    float mug = (l0[2 * gg] + l0[2 * gg + 1]) * (1.f / 32768.f);
    float var = l0[8 + gg] * (1.f / 32768.f) - mug * mug;
    pooled[c] = fmaf((mean_c - mug) * rsqrtf(var + 1e-5f), gn_s[8 + c], gn_b[8 + c]);
  }

  __shared__ float sH1[32];
  if (lane < 32) {
    float h = b1[lane];
#pragma unroll
    for (int c = 0; c < 8; ++c) h = fmaf(pooled[c], w1[c * 32 + lane], h);
    float t = 0.7978845608028654f * fmaf(0.044715f * h * h, h, h);
    sH1[lane] = 0.5f * h * (1.f + tanhf(t));
  }
  __syncthreads();
  for (int o = lane; o < 100; o += 64) {
    float v = b2[o];
#pragma unroll
    for (int j = 0; j < 32; ++j) v = fmaf(sH1[j], w2[j * 100 + o], v);
    out[b * 100 + o] = v;
  }
}

extern "C" void kernel_launch(void* const* d_in, const int* in_sizes, int n_in,
                              void* d_out, int out_size, void* d_ws, size_t ws_size,
                              hipStream_t stream) {
  const float* X       = (const float*)d_in[0];
  const float* stem_w  = (const float*)d_in[1];
  const float* stem_sc = (const float*)d_in[2];
  const float* stem_bi = (const float*)d_in[3];
  const float* gate_w  = (const float*)d_in[4];
  const float* gate_b  = (const float*)d_in[5];
  const float* exp_w   = (const float*)d_in[6];
  const float* exp_b   = (const float*)d_in[7];
  const float* gn_s    = (const float*)d_in[8];
  const float* gn_b    = (const float*)d_in[9];
  const float* w1      = (const float*)d_in[10];
  const float* b1      = (const float*)d_in[11];
  const float* w2      = (const float*)d_in[12];
  const float* b2      = (const float*)d_in[13];
  float* out = (float*)d_out;

  char* ws = (char*)d_ws;
  int* route_e      = (int*)(ws + 0);            // 512 ints
  int* route_cpre   = (int*)(ws + 2048);         // 512 ints
  int* route_Ce     = (int*)(ws + 4096);         // 16 ints
  float* route_gate = (float*)(ws + 4160);       // 512 floats
  float* wT         = (float*)(ws + 8192);       // 9216 floats
  float* stemT      = (float*)(ws + 45056);      // 216 floats
  float* blk_sums   = (float*)(ws + 49152);      // 4096*12 floats (192 KiB)

  routing_kernel<<<1, 256, 0, stream>>>(gate_w, gate_b, stem_w, exp_w,
                                        route_e, route_gate, route_cpre,
                                        route_Ce, stemT, wT, out + 6400);
  token_kernel<<<4096, 256, 0, stream>>>(X, stemT, stem_sc, stem_bi, wT,
                                         exp_b, gn_s, gn_b, route_e, route_gate,
                                         route_cpre, route_Ce, blk_sums);
  finish_kernel<<<64, 64, 0, stream>>>(blk_sums, gn_s, gn_b, w1, b1, w2, b2,
                                       out);
}

// Round 3
// 87.961 us; speedup vs baseline: 1.4328x; 1.4328x over previous
//
#include <hip/hip_runtime.h>
#include <math.h>

#define CAPV 2560

__device__ __forceinline__ float wave_sum64(float v) {
#pragma unroll
  for (int o = 32; o; o >>= 1) v += __shfl_xor(v, o, 64);
  return v;
}

__device__ __forceinline__ float silu_f(float t) {
  return t * __builtin_amdgcn_rcpf(1.f + __expf(-t));
}

// ---------------- routing: 1 block, 256 threads (one per patch) ----------------
// Also pre-transposes stem/expert weights into [ci][co][12]-padded layout.
__global__ __launch_bounds__(256) void routing_kernel(
    const float* __restrict__ gate_w, const float* __restrict__ gate_b,
    const float* __restrict__ stem_w, const float* __restrict__ exp_w,
    int* __restrict__ route_e, float* __restrict__ route_gate,
    int* __restrict__ route_cpre, int* __restrict__ route_Ce,
    float* __restrict__ stemT2, float* __restrict__ wT2,
    float* __restrict__ d_scalars) {
  const int p = threadIdx.x;            // patch index 0..255
  const int lane = p & 63, wv = p >> 6; // 4 waves
  const int hp = p >> 4, wp = p & 15;

  // stemT2[(ci*8+co)*12 + t] = stem_w[(co*3+ci)*9 + t]
  if (p < 216) {
    int ci = p / 72, r = p % 72;
    int co = r / 9, t = r % 9;
    stemT2[(ci * 8 + co) * 12 + t] = stem_w[p];  // p == (co*3+ci)*9+t? no:
  }
  // careful: do the stem transpose with explicit source index
  if (p < 216) {
    int co = p / 27, r = p % 27;
    int ci = r / 9, t = r % 9;
    stemT2[(ci * 8 + co) * 12 + t] = stem_w[p];  // p == (co*3+ci)*9 + t
  }
  // wT2[((le*8+ci)*8+co)*12 + t] = exp_w[((le*8+co)*8+ci)*9 + t]
  for (int i = p; i < 9216; i += 256) {
    int le = i / 576, r = i % 576;
    int co = r / 72, r2 = r % 72;
    int ci = r2 / 9, t = r2 % 9;
    wT2[(((le * 8) + ci) * 8 + co) * 12 + t] = exp_w[i];  // i == ((le*8+co)*8+ci)*9+t
  }

  // pooled fourier features (mean over 8x8 patch)
  float pool[18];
  {
    float my = 0.f, mx_ = 0.f;
    float msy[4] = {0, 0, 0, 0}, mcy[4] = {0, 0, 0, 0};
    float msx[4] = {0, 0, 0, 0}, mcx[4] = {0, 0, 0, 0};
#pragma unroll
    for (int r = 0; r < 8; ++r) {
      float yv = -1.f + (2.f / 127.f) * (float)(hp * 8 + r);
      float xv = -1.f + (2.f / 127.f) * (float)(wp * 8 + r);
      my += yv; mx_ += xv;
#pragma unroll
      for (int k = 0; k < 4; ++k) {
        float fr = 3.14159265358979323846f * (float)(1 << k);
        msy[k] += sinf(fr * yv); mcy[k] += cosf(fr * yv);
        msx[k] += sinf(fr * xv); mcx[k] += cosf(fr * xv);
      }
    }
    pool[0] = my * 0.125f; pool[1] = mx_ * 0.125f;
#pragma unroll
    for (int k = 0; k < 4; ++k) {
      pool[2 + 4 * k] = msy[k] * 0.125f;
      pool[3 + 4 * k] = mcy[k] * 0.125f;
      pool[4 + 4 * k] = msx[k] * 0.125f;
      pool[5 + 4 * k] = mcx[k] * 0.125f;
    }
  }

  __shared__ float sWP[4][8];
  __shared__ float sWZ[4];
  __shared__ int sWCnt[4][8];
  __shared__ float sMeanP[8], sFrac[8];
  __shared__ float sAcc[2];
  if (p == 0) { sAcc[0] = 0.f; sAcc[1] = 0.f; }

  for (int l = 0; l < 2; ++l) {
    float logit[8];
#pragma unroll
    for (int e = 0; e < 8; ++e) logit[e] = gate_b[l * 8 + e];
#pragma unroll
    for (int c = 0; c < 18; ++c) {
      float pl = pool[c];
#pragma unroll
      for (int e = 0; e < 8; ++e)
        logit[e] = fmaf(pl, gate_w[(l * 18 + c) * 8 + e], logit[e]);
    }
    float mxv = logit[0]; int em = 0;
#pragma unroll
    for (int e = 1; e < 8; ++e)
      if (logit[e] > mxv) { mxv = logit[e]; em = e; }
    float pr[8]; float se = 0.f;
#pragma unroll
    for (int e = 0; e < 8; ++e) { pr[e] = expf(logit[e] - mxv); se += pr[e]; }
    float inv = 1.f / se;
#pragma unroll
    for (int e = 0; e < 8; ++e) pr[e] *= inv;
    float lse = mxv + logf(se);
    float gate_val = inv;

    unsigned long long meq[8];
#pragma unroll
    for (int e = 0; e < 8; ++e) meq[e] = __ballot(em == e);
    unsigned long long mm = meq[0];
#pragma unroll
    for (int e = 1; e < 8; ++e) mm = (em == e) ? meq[e] : mm;
    unsigned long long below = (2ull << lane) - 1ull;
    int cpre_w = (int)__popcll(mm & below);
    if (lane < 8) {
      unsigned long long t = meq[0];
#pragma unroll
      for (int e = 1; e < 8; ++e) t = (lane == e) ? meq[e] : t;
      sWCnt[wv][lane] = (int)__popcll(t);
    }
    float z2 = wave_sum64(lse * lse);
    if (lane == 0) sWZ[wv] = z2;
#pragma unroll
    for (int e = 0; e < 8; ++e) {
      float s = wave_sum64(pr[e]);
      if (lane == 0) sWP[wv][e] = s;
    }
    __syncthreads();

    int cpre = cpre_w;
#pragma unroll
    for (int w2 = 0; w2 < 4; ++w2)
      if (w2 < wv) cpre += sWCnt[w2][em];

    route_e[l * 256 + p] = em;
    route_gate[l * 256 + p] = gate_val;
    route_cpre[l * 256 + p] = cpre;

    if (p < 8) {
      int ce = sWCnt[0][p] + sWCnt[1][p] + sWCnt[2][p] + sWCnt[3][p];
      route_Ce[l * 8 + p] = ce;
      int kept = 0;
      for (int bb = 0; bb < 64; ++bb) {
        int r = CAPV - bb * ce;
        r = r < 0 ? 0 : r;
        kept += (r < ce ? r : ce);
      }
      sFrac[p] = (float)kept * (1.f / 16384.f);
      sMeanP[p] = (sWP[0][p] + sWP[1][p] + sWP[2][p] + sWP[3][p]) * (1.f / 256.f);
    }
    __syncthreads();
    if (p == 0) {
      float s = 0.f;
#pragma unroll
      for (int e = 0; e < 8; ++e) s += sMeanP[e] * sFrac[e];
      sAcc[1] += 8.f * s;
      sAcc[0] += (sWZ[0] + sWZ[1] + sWZ[2] + sWZ[3]) * (1.f / 256.f);
    }
    __syncthreads();
  }
  if (p == 0) { d_scalars[0] = sAcc[0]; d_scalars[1] = sAcc[1]; }
}

// ---------------- token kernel: 4 tokens / block, lane = (y, co) ----------------
__global__ __launch_bounds__(256) void token_kernel(
    const float* __restrict__ X,
    const float* __restrict__ stemT2, const float* __restrict__ stem_sc,
    const float* __restrict__ stem_bi,
    const float* __restrict__ wT2, const float* __restrict__ exp_b,
    const float* __restrict__ gn_s, const float* __restrict__ gn_b,
    const int* __restrict__ route_e, const float* __restrict__ route_gate,
    const int* __restrict__ route_cpre, const int* __restrict__ route_Ce,
    float* __restrict__ blk_sums) {
  const int g = blockIdx.x;
  const int b = g >> 6, r6 = g & 63;
  const int hp = r6 >> 2, wq = r6 & 3;      // 4 horizontally adjacent patches
  const int tid = threadIdx.x;
  const int w = tid >> 6, lane = tid & 63;  // wave == token
  const int y = lane >> 3, co = lane & 7;   // lane = output row x channel
  const int p = hp * 16 + wq * 4 + w;
  const int xb = w * 8;

  __shared__ float sX[3][10][36];     // shared halo, rows 144B-aligned
  __shared__ float sT[4][8][10][12];  // stride 12: 16B rows, conflict-free banks
  __shared__ float sRed[4][12];

  // zero border rows 0 and 9 of own token (cols 0..11); interior rows are
  // always fully written (with zeros in cols 0,9,10,11) by the row stores.
  if (lane < 48) {
    int q = lane % 3, rr = (lane / 3) & 1, ch = lane / 6;
    float4 z = {0.f, 0.f, 0.f, 0.f};
    *(float4*)&sT[w][ch][rr * 9][q * 4] = z;
  }

  // cooperative coalesced halo load: 3 x 10 x 34 region
  const int gy0 = hp * 8 - 1, gx0 = wq * 32 - 1;
#pragma unroll
  for (int k = 0; k < 4; ++k) {
    int i = tid + k * 256;
    if (i < 1020) {
      int ci = i / 340, rem = i - ci * 340;
      int r = rem / 34, c = rem - r * 34;
      int gy = gy0 + r, gx = gx0 + c;
      float v = 0.f;
      if (gy >= 0 && gy < 128 && gx >= 0 && gx < 128)
        v = X[((b * 3 + ci) * 128 + gy) * 128 + gx];
      sX[ci][r][c] = v;
    }
  }
  __syncthreads();

  // ---- stem: lane computes row y, channel co, 8 pixels ----
  {
    float acc[8];
#pragma unroll
    for (int px = 0; px < 8; ++px) acc[px] = 0.f;
#pragma unroll
    for (int ci = 0; ci < 3; ++ci) {
      float r[3][10];
#pragma unroll
      for (int dy = 0; dy < 3; ++dy) {
        const float* rp = &sX[ci][y + dy][xb];
        float4 q0 = *(const float4*)rp;
        float4 q1 = *(const float4*)(rp + 4);
        float2 q2 = *(const float2*)(rp + 8);
        r[dy][0] = q0.x; r[dy][1] = q0.y; r[dy][2] = q0.z; r[dy][3] = q0.w;
        r[dy][4] = q1.x; r[dy][5] = q1.y; r[dy][6] = q1.z; r[dy][7] = q1.w;
        r[dy][8] = q2.x; r[dy][9] = q2.y;
      }
      const float* wp = stemT2 + (ci * 8 + co) * 12;
      float4 wa = *(const float4*)wp;
      float4 wbv = *(const float4*)(wp + 4);
      float w8 = wp[8];
      float ws9[9] = {wa.x, wa.y, wa.z, wa.w, wbv.x, wbv.y, wbv.z, wbv.w, w8};
#pragma unroll
      for (int dy = 0; dy < 3; ++dy)
#pragma unroll
        for (int dx = 0; dx < 3; ++dx) {
          float wv = ws9[dy * 3 + dx];
#pragma unroll
          for (int px = 0; px < 8; ++px)
            acc[px] = fmaf(wv, r[dy][px + dx], acc[px]);
        }
    }
    float sc = stem_sc[co], bi = stem_bi[co];
    float s0 = silu_f(fmaf(acc[0], sc, bi));
    float s1 = silu_f(fmaf(acc[1], sc, bi));
    float s2 = silu_f(fmaf(acc[2], sc, bi));
    float s3 = silu_f(fmaf(acc[3], sc, bi));
    float s4 = silu_f(fmaf(acc[4], sc, bi));
    float s5 = silu_f(fmaf(acc[5], sc, bi));
    float s6 = silu_f(fmaf(acc[6], sc, bi));
    float s7 = silu_f(fmaf(acc[7], sc, bi));
    float* dst = &sT[w][co][y + 1][0];
    float4 o0 = {0.f, s0, s1, s2};
    float4 o1 = {s3, s4, s5, s6};
    float4 o2 = {s7, 0.f, 0.f, 0.f};
    *(float4*)dst = o0;
    *(float4*)(dst + 4) = o1;
    *(float4*)(dst + 8) = o2;
  }
  // sT[w] is wave-private; wave-synchronous DS ordering suffices (no barrier).

  float a[8];
#pragma unroll
  for (int l = 0; l < 2; ++l) {
    int e = route_e[l * 256 + p];
    e = __builtin_amdgcn_readfirstlane(e);
    float gp = route_gate[l * 256 + p];
    int cpre = route_cpre[l * 256 + p];
    int Ce = route_Ce[l * 8 + e];
    float gate = (b * Ce + cpre <= CAPV) ? gp : 0.f;
    const int le = l * 8 + e;

#pragma unroll
    for (int px = 0; px < 8; ++px) a[px] = 0.f;
#pragma unroll
    for (int ci = 0; ci < 8; ++ci) {
      float r[3][10];
#pragma unroll
      for (int dy = 0; dy < 3; ++dy) {
        const float* rp = &sT[w][ci][y + dy][0];
        float4 q0 = *(const float4*)rp;
        float4 q1 = *(const float4*)(rp + 4);
        float2 q2 = *(const float2*)(rp + 8);
        r[dy][0] = q0.x; r[dy][1] = q0.y; r[dy][2] = q0.z; r[dy][3] = q0.w;
        r[dy][4] = q1.x; r[dy][5] = q1.y; r[dy][6] = q1.z; r[dy][7] = q1.w;
        r[dy][8] = q2.x; r[dy][9] = q2.y;
      }
      const float* wp = wT2 + ((le * 8 + ci) * 8 + co) * 12;
      float4 wa = *(const float4*)wp;
      float4 wbv = *(const float4*)(wp + 4);
      float w8 = wp[8];
      float ws9[9] = {wa.x, wa.y, wa.z, wa.w, wbv.x, wbv.y, wbv.z, wbv.w, w8};
#pragma unroll
      for (int dy = 0; dy < 3; ++dy)
#pragma unroll
        for (int dx = 0; dx < 3; ++dx) {
          float wv = ws9[dy * 3 + dx];
#pragma unroll
          for (int px = 0; px < 8; ++px)
            a[px] = fmaf(wv, r[dy][px + dx], a[px]);
        }
    }
    float bias = exp_b[le * 8 + co];
#pragma unroll
    for (int px = 0; px < 8; ++px) a[px] = silu_f(a[px] + bias) * gate;

    if (l == 0) {
      // per-token GroupNorm: groups = channel pairs; sum over bit0(co), bits3-5(y)
      float s = 0.f, q = 0.f;
#pragma unroll
      for (int px = 0; px < 8; ++px) { s += a[px]; q += a[px] * a[px]; }
      s += __shfl_xor(s, 1, 64);  q += __shfl_xor(q, 1, 64);
      s += __shfl_xor(s, 8, 64);  q += __shfl_xor(q, 8, 64);
      s += __shfl_xor(s, 16, 64); q += __shfl_xor(q, 16, 64);
      s += __shfl_xor(s, 32, 64); q += __shfl_xor(q, 32, 64);
      float mu = s * (1.f / 128.f);
      float var = q * (1.f / 128.f) - mu * mu;
      float inv = rsqrtf(var + 1e-5f);
      float sc2 = inv * gn_s[co];
      float bi2 = fmaf(-mu, sc2, gn_b[co]);
      float n0 = fmaf(a[0], sc2, bi2), n1 = fmaf(a[1], sc2, bi2);
      float n2 = fmaf(a[2], sc2, bi2), n3 = fmaf(a[3], sc2, bi2);
      float n4 = fmaf(a[4], sc2, bi2), n5 = fmaf(a[5], sc2, bi2);
      float n6 = fmaf(a[6], sc2, bi2), n7 = fmaf(a[7], sc2, bi2);
      float* dst = &sT[w][co][y + 1][0];
      float4 o0 = {0.f, n0, n1, n2};
      float4 o1 = {n3, n4, n5, n6};
      float4 o2 = {n7, 0.f, 0.f, 0.f};
      *(float4*)dst = o0;
      *(float4*)(dst + 4) = o1;
      *(float4*)(dst + 8) = o2;
    }
  }

  // final per-token partials: channel sums (8) + group sum-of-squares (4)
  {
    float s = 0.f, q = 0.f;
#pragma unroll
    for (int px = 0; px < 8; ++px) { s += a[px]; q += a[px] * a[px]; }
    s += __shfl_xor(s, 8, 64);
    s += __shfl_xor(s, 16, 64);
    s += __shfl_xor(s, 32, 64);
    q += __shfl_xor(q, 1, 64);
    q += __shfl_xor(q, 8, 64);
    q += __shfl_xor(q, 16, 64);
    q += __shfl_xor(q, 32, 64);
    if (lane < 8) sRed[w][lane] = s;
    if (lane < 8 && !(lane & 1)) sRed[w][8 + (lane >> 1)] = q;
  }
  __syncthreads();
  if (tid < 12)
    blk_sums[(size_t)g * 12 + tid] =
        sRed[0][tid] + sRed[1][tid] + sRed[2][tid] + sRed[3][tid];
}

// ---------------- finish: per-image GN-folded pooling + MLP head ----------------
__global__ __launch_bounds__(64) void finish_kernel(
    const float* __restrict__ blk_sums,
    const float* __restrict__ gn_s, const float* __restrict__ gn_b,
    const float* __restrict__ w1, const float* __restrict__ b1,
    const float* __restrict__ w2, const float* __restrict__ b2,
    float* __restrict__ out) {
  const int b = blockIdx.x;
  const int lane = threadIdx.x;

  const float4* s4 = (const float4*)(blk_sums + (size_t)(b * 64 + lane) * 12);
  float4 a0 = s4[0], a1 = s4[1], a2 = s4[2];
  float l0[12] = {a0.x, a0.y, a0.z, a0.w, a1.x, a1.y, a1.z, a1.w,
                  a2.x, a2.y, a2.z, a2.w};
#pragma unroll
  for (int j = 0; j < 12; ++j) l0[j] = wave_sum64(l0[j]);

  float pooled[8];
#pragma unroll
  for (int c = 0; c < 8; ++c) {
    int gg = c >> 1;
    float mean_c = l0[c] * (1.f / 16384.f);
    float mug = (l0[2 * gg] + l0[2 * gg + 1]) * (1.f / 32768.f);
    float var = l0[8 + gg] * (1.f / 32768.f) - mug * mug;
    pooled[c] = fmaf((mean_c - mug) * rsqrtf(var + 1e-5f), gn_s[8 + c], gn_b[8 + c]);
  }

  __shared__ float sH1[32];
  if (lane < 32) {
    float h = b1[lane];
#pragma unroll
    for (int c = 0; c < 8; ++c) h = fmaf(pooled[c], w1[c * 32 + lane], h);
    float t = 0.7978845608028654f * fmaf(0.044715f * h * h, h, h);
    sH1[lane] = 0.5f * h * (1.f + tanhf(t));
  }
  __syncthreads();
  for (int o = lane; o < 100; o += 64) {
    float v = b2[o];
#pragma unroll
    for (int j = 0; j < 32; ++j) v = fmaf(sH1[j], w2[j * 100 + o], v);
    out[b * 100 + o] = v;
  }
}

extern "C" void kernel_launch(void* const* d_in, const int* in_sizes, int n_in,
                              void* d_out, int out_size, void* d_ws, size_t ws_size,
                              hipStream_t stream) {
  const float* X       = (const float*)d_in[0];
  const float* stem_w  = (const float*)d_in[1];
  const float* stem_sc = (const float*)d_in[2];
  const float* stem_bi = (const float*)d_in[3];
  const float* gate_w  = (const float*)d_in[4];
  const float* gate_b  = (const float*)d_in[5];
  const float* exp_w   = (const float*)d_in[6];
  const float* exp_b   = (const float*)d_in[7];
  const float* gn_s    = (const float*)d_in[8];
  const float* gn_b    = (const float*)d_in[9];
  const float* w1      = (const float*)d_in[10];
  const float* b1      = (const float*)d_in[11];
  const float* w2      = (const float*)d_in[12];
  const float* b2      = (const float*)d_in[13];
  float* out = (float*)d_out;

  char* ws = (char*)d_ws;
  int* route_e      = (int*)(ws + 0);            // 512 ints
  int* route_cpre   = (int*)(ws + 2048);         // 512 ints
  int* route_Ce     = (int*)(ws + 4096);         // 16 ints
  float* route_gate = (float*)(ws + 4160);       // 512 floats
  float* stemT2     = (float*)(ws + 8192);       // 288 floats
  float* wT2        = (float*)(ws + 16384);      // 12288 floats (48 KiB)
  float* blk_sums   = (float*)(ws + 65536);      // 4096*12 floats (192 KiB)

  routing_kernel<<<1, 256, 0, stream>>>(gate_w, gate_b, stem_w, exp_w,
                                        route_e, route_gate, route_cpre,
                                        route_Ce, stemT2, wT2, out + 6400);
  token_kernel<<<4096, 256, 0, stream>>>(X, stemT2, stem_sc, stem_bi, wT2,
                                         exp_b, gn_s, gn_b, route_e, route_gate,
                                         route_cpre, route_Ce, blk_sums);
  finish_kernel<<<64, 64, 0, stream>>>(blk_sums, gn_s, gn_b, w1, b1, w2, b2,
                                       out);
}